// Round 5
// baseline (820.388 us; speedup 1.0000x reference)
//
#include <hip/hip_runtime.h>
#include <math.h>

// EnvAwareRouter: B=524288, C=13, T=24, H=64, E=8, K=3, tau=1, eps=1e-10
// Output: concat[ mask(B,E), probs(B,E) ] f32
//
// R5 = R4 numerics with the register/occupancy balance fixed.
//  - __launch_bounds__(256, 6): VGPR cap 85 (R4's (256,8) cap=64 -> compiler
//    picked 32 and spilled 470 B/thread: WRITE_SIZE 32->247 MB, VALUBusy 84).
//    Packed code needs ~60-70 VGPR: x[24] + a2[16] + fp64 y[16] + addressing.
//  - v_pk_fma_f32 via v2f in fc1/c_mlp (halves fc1 issue count)
//  - A&S erf gelu (1.5e-7), custom fp64 gumbel log (sqrt2-centered, ~1e-13),
//    fp64 only for gumbel+ordering. Validated numerics (absmax 0.0039 R2-R4).

constexpr int Bn = 524288, Cn = 13, Tn = 24, Hn = 64, En = 8, Kn = 3;

typedef float v2f __attribute__((ext_vector_type(2)));

#define RCPF(x) __builtin_amdgcn_rcpf(x)
#define EXP2F(x) __builtin_amdgcn_exp2f(x)

// gelu(a) = a * (0.5 + 0.5*erf(a/sqrt(2))), erf via Abramowitz-Stegun 7.1.26
__device__ __forceinline__ float fast_gelu(float a) {
    const float p  = 0.3275911f;
    const float c1 = 0.254829592f, c2 = -0.284496736f, c3 = 1.421413741f,
                c4 = -1.453152027f, c5 = 1.061405429f;
    float az = fabsf(a) * 0.70710678118654752f;          // z = |a|/sqrt(2)
    float t  = RCPF(fmaf(p, az, 1.0f));
    float poly = fmaf(fmaf(fmaf(fmaf(c5, t, c4), t, c3), t, c2), t, c1) * t;
    float ez = EXP2F(az * az * -1.4426950408889634f);    // exp(-a^2/2)
    float e  = fmaf(-poly, ez, 1.0f);                    // erf(z)
    float es = copysignf(e, a);
    return a * fmaf(es, 0.5f, 0.5f);
}

// fp64 ln(x) for x in (1e-10, 64), rel err ~1e-13 (sqrt2-centered mantissa;
// x near 1 -> m=x, e=0, m-1.0 exact).
__device__ __forceinline__ double fast_log(double x) {
    long long bits = __double_as_longlong(x);
    int e = (int)(bits >> 52) - 1023;
    double m = __longlong_as_double((bits & 0x000FFFFFFFFFFFFFLL) |
                                    0x3FF0000000000000LL);
    if (m > 1.4142135623730951) { m *= 0.5; e += 1; }
    double num = m - 1.0, den = m + 1.0;
    double r = (double)RCPF((float)den);
    r = r * (2.0 - den * r);
    r = r * (2.0 - den * r);
    double s = num * r, s2 = s * s;
    double q = fma(s2, 1.0 / 15.0, 1.0 / 13.0);
    q = fma(s2, q, 1.0 / 11.0);
    q = fma(s2, q, 1.0 / 9.0);
    q = fma(s2, q, 1.0 / 7.0);
    q = fma(s2, q, 1.0 / 5.0);
    q = fma(s2, q, 1.0 / 3.0);
    q = fma(s2, q, 1.0);
    return fma((double)e, 0.6931471805599453, (s + s) * q);
}

__global__ __launch_bounds__(256, 6) void router_kernel(
    const float* __restrict__ ctx, const float* __restrict__ u,
    const float* __restrict__ tw1, const float* __restrict__ tb1,
    const float* __restrict__ tw2, const float* __restrict__ tb2,
    const float* __restrict__ cw1, const float* __restrict__ cb1,
    const float* __restrict__ cw2, const float* __restrict__ cb2,
    float* __restrict__ out)
{
    __shared__ float tv_lds[256 * Cn];   // stride 13 (odd) -> bank-conflict-free

    const int b = blockIdx.x * 256 + threadIdx.x;
    const float* xb = ctx + (long)b * (Cn * Tn);
    const float tb2v = tb2[0];

    // ---- t_mlp per context c: t[c] = gelu(x @ tw1 + tb1) @ tw2 + tb2 ----
    #pragma unroll 1
    for (int c = 0; c < Cn; ++c) {
        float x[Tn];
        const float4* xp = reinterpret_cast<const float4*>(xb + c * Tn);
        #pragma unroll
        for (int i = 0; i < Tn / 4; ++i) {
            float4 v = xp[i];
            x[4 * i + 0] = v.x; x[4 * i + 1] = v.y;
            x[4 * i + 2] = v.z; x[4 * i + 3] = v.w;
        }

        float tacc = 0.0f;
        #pragma unroll 1
        for (int hb = 0; hb < Hn; hb += 16) {
            v2f a2[8];
            const v2f* tb1v = reinterpret_cast<const v2f*>(tb1 + hb);
            #pragma unroll
            for (int j = 0; j < 8; ++j) a2[j] = tb1v[j];
            #pragma unroll
            for (int t = 0; t < Tn; ++t) {
                const float xv = x[t];
                v2f xs = { xv, xv };
                const v2f* wv = reinterpret_cast<const v2f*>(tw1 + t * Hn + hb);
                #pragma unroll
                for (int j = 0; j < 8; ++j)
                    a2[j] = __builtin_elementwise_fma(xs, wv[j], a2[j]);
            }
            #pragma unroll
            for (int j = 0; j < 8; ++j) {
                tacc = fmaf(fast_gelu(a2[j].x), tw2[hb + 2 * j + 0], tacc);
                tacc = fmaf(fast_gelu(a2[j].y), tw2[hb + 2 * j + 1], tacc);
            }
        }
        tv_lds[threadIdx.x * Cn + c] = tacc + tb2v;
    }

    // pull t values back (static offsets -> registers)
    float tv[Cn];
    #pragma unroll
    for (int c = 0; c < Cn; ++c) tv[c] = tv_lds[threadIdx.x * Cn + c];

    // ---- c_mlp (fp32, packed): logits = gelu(t @ cw1 + cb1) @ cw2 + cb2 ----
    v2f logits2[4];
    const v2f* cb2v = reinterpret_cast<const v2f*>(cb2);
    #pragma unroll
    for (int e2 = 0; e2 < 4; ++e2) logits2[e2] = cb2v[e2];

    #pragma unroll 1
    for (int h2 = 0; h2 < Hn / 2; ++h2) {
        v2f acc2 = reinterpret_cast<const v2f*>(cb1)[h2];
        #pragma unroll
        for (int c = 0; c < Cn; ++c) {
            v2f ts = { tv[c], tv[c] };
            acc2 = __builtin_elementwise_fma(
                ts, reinterpret_cast<const v2f*>(cw1 + c * Hn)[h2], acc2);
        }
        float g0 = fast_gelu(acc2.x), g1 = fast_gelu(acc2.y);
        v2f gs0 = { g0, g0 }, gs1 = { g1, g1 };
        const v2f* w20 = reinterpret_cast<const v2f*>(cw2 + (2 * h2 + 0) * En);
        const v2f* w21 = reinterpret_cast<const v2f*>(cw2 + (2 * h2 + 1) * En);
        #pragma unroll
        for (int e2 = 0; e2 < 4; ++e2) {
            logits2[e2] = __builtin_elementwise_fma(gs0, w20[e2], logits2[e2]);
            logits2[e2] = __builtin_elementwise_fma(gs1, w21[e2], logits2[e2]);
        }
    }
    float logits[En];
    #pragma unroll
    for (int e2 = 0; e2 < 4; ++e2) {
        logits[2 * e2 + 0] = logits2[e2].x;
        logits[2 * e2 + 1] = logits2[e2].y;
    }

    // ---- gumbel (custom fp64 logs), y = logits + g ----
    const float4* up = reinterpret_cast<const float4*>(u + (long)b * En);
    float4 u0 = up[0], u1 = up[1];
    float uv[En] = { u0.x, u0.y, u0.z, u0.w, u1.x, u1.y, u1.z, u1.w };

    double y[En];
    #pragma unroll
    for (int e = 0; e < En; ++e) {
        double w = -fast_log((double)uv[e]);
        y[e] = (double)logits[e] - fast_log(w + 1e-10);   // tau = 1
    }

    // ---- softmax in fp32 (probs compared at bf16 tolerance) ----
    double m = y[0];
    #pragma unroll
    for (int e = 1; e < En; ++e) m = fmax(m, y[e]);
    float p[En], s = 0.0f;
    #pragma unroll
    for (int e = 0; e < En; ++e) {
        p[e] = EXP2F((float)(y[e] - m) * 1.4426950408889634f);
        s += p[e];
    }
    float inv = RCPF(s);

    // ---- top-3 on y (fp64 ordering == probs ordering), bitmask ----
    unsigned sel = 0u;
    #pragma unroll
    for (int k = 0; k < Kn; ++k) {
        int best = 0;
        double bv = -1.0e300;
        #pragma unroll
        for (int e = 0; e < En; ++e) {
            bool ok = (((sel >> e) & 1u) == 0u) && (y[e] > bv);
            bv = ok ? y[e] : bv;
            best = ok ? e : best;
        }
        sel |= (1u << best);
    }

    // ---- stores ----
    float4* om = reinterpret_cast<float4*>(out + (long)b * En);
    om[0] = make_float4((sel >> 0) & 1u, (sel >> 1) & 1u,
                        (sel >> 2) & 1u, (sel >> 3) & 1u);
    om[1] = make_float4((sel >> 4) & 1u, (sel >> 5) & 1u,
                        (sel >> 6) & 1u, (sel >> 7) & 1u);
    float4* op = reinterpret_cast<float4*>(out + (long)Bn * En + (long)b * En);
    op[0] = make_float4(p[0] * inv, p[1] * inv, p[2] * inv, p[3] * inv);
    op[1] = make_float4(p[4] * inv, p[5] * inv, p[6] * inv, p[7] * inv);
}

extern "C" void kernel_launch(void* const* d_in, const int* in_sizes, int n_in,
                              void* d_out, int out_size, void* d_ws, size_t ws_size,
                              hipStream_t stream) {
    const float* ctx = (const float*)d_in[0];
    const float* u   = (const float*)d_in[1];
    const float* tw1 = (const float*)d_in[2];
    const float* tb1 = (const float*)d_in[3];
    const float* tw2 = (const float*)d_in[4];
    const float* tb2 = (const float*)d_in[5];
    const float* cw1 = (const float*)d_in[6];
    const float* cb1 = (const float*)d_in[7];
    const float* cw2 = (const float*)d_in[8];
    const float* cb2 = (const float*)d_in[9];
    float* out = (float*)d_out;

    dim3 grid(Bn / 256), block(256);
    router_kernel<<<grid, block, 0, stream>>>(ctx, u, tw1, tb1, tw2, tb2,
                                              cw1, cb1, cw2, cb2, out);
}

// Round 6
// 468.640 us; speedup vs baseline: 1.7506x; 1.7506x over previous
//
#include <hip/hip_runtime.h>
#include <math.h>

// EnvAwareRouter: B=524288, C=13, T=24, H=64, E=8, K=3, tau=1, eps=1e-10
// Output: concat[ mask(B,E), probs(B,E) ] f32
//
// R6: two-phase restructure (kills the R4/R5 spill pathology structurally).
//  Phase 1: (b,c)-row-parallel fc1+gelu+fc2. Block owns 256 b's = 3328 rows;
//    iteration k, thread tid -> row g = b0*13 + k*256 + tid. Lean live state
//    (x[24]+a2[16], no fp64 in scope) -> no spills; consecutive lanes read
//    consecutive 96-B x rows -> fully coalesced (R1-R5 strode 1248 B/lane).
//    Results to LDS tv[g - g0].
//  Phase 2: per-b c_mlp+gumbel+softmax+topk (scalar fp32 + custom fp64 logs,
//    validated R4/R5). tv[tid*13+c]: stride-13 -> 2 lanes/bank (free).
//  pk-FMA (v2f) only in phase-1 fc1 where register pressure is low.

constexpr int Bn = 524288, Cn = 13, Tn = 24, Hn = 64, En = 8, Kn = 3;

typedef float v2f __attribute__((ext_vector_type(2)));

#define RCPF(x) __builtin_amdgcn_rcpf(x)
#define EXP2F(x) __builtin_amdgcn_exp2f(x)

// gelu(a) = a * (0.5 + 0.5*erf(a/sqrt(2))), erf via Abramowitz-Stegun 7.1.26
__device__ __forceinline__ float fast_gelu(float a) {
    const float p  = 0.3275911f;
    const float c1 = 0.254829592f, c2 = -0.284496736f, c3 = 1.421413741f,
                c4 = -1.453152027f, c5 = 1.061405429f;
    float az = fabsf(a) * 0.70710678118654752f;          // z = |a|/sqrt(2)
    float t  = RCPF(fmaf(p, az, 1.0f));
    float poly = fmaf(fmaf(fmaf(fmaf(c5, t, c4), t, c3), t, c2), t, c1) * t;
    float ez = EXP2F(az * az * -1.4426950408889634f);    // exp(-a^2/2)
    float e  = fmaf(-poly, ez, 1.0f);                    // erf(z)
    float es = copysignf(e, a);
    return a * fmaf(es, 0.5f, 0.5f);
}

// fp64 ln(x) for x in (1e-10, 64), rel err ~1e-13 (sqrt2-centered mantissa;
// x near 1 -> m=x, e=0, m-1.0 exact). Validated R4/R5.
__device__ __forceinline__ double fast_log(double x) {
    long long bits = __double_as_longlong(x);
    int e = (int)(bits >> 52) - 1023;
    double m = __longlong_as_double((bits & 0x000FFFFFFFFFFFFFLL) |
                                    0x3FF0000000000000LL);
    if (m > 1.4142135623730951) { m *= 0.5; e += 1; }
    double num = m - 1.0, den = m + 1.0;
    double r = (double)RCPF((float)den);
    r = r * (2.0 - den * r);
    r = r * (2.0 - den * r);
    double s = num * r, s2 = s * s;
    double q = fma(s2, 1.0 / 15.0, 1.0 / 13.0);
    q = fma(s2, q, 1.0 / 11.0);
    q = fma(s2, q, 1.0 / 9.0);
    q = fma(s2, q, 1.0 / 7.0);
    q = fma(s2, q, 1.0 / 5.0);
    q = fma(s2, q, 1.0 / 3.0);
    q = fma(s2, q, 1.0);
    return fma((double)e, 0.6931471805599453, (s + s) * q);
}

__global__ __launch_bounds__(256, 4) void router_kernel(
    const float* __restrict__ ctx, const float* __restrict__ u,
    const float* __restrict__ tw1, const float* __restrict__ tb1,
    const float* __restrict__ tw2, const float* __restrict__ tb2,
    const float* __restrict__ cw1, const float* __restrict__ cb1,
    const float* __restrict__ cw2, const float* __restrict__ cb2,
    float* __restrict__ out)
{
    __shared__ float tv[256 * Cn];   // 13312 B; phase1 writes stride-1

    const int tid = threadIdx.x;
    const long b0 = (long)blockIdx.x * 256;
    const float tb2v = tb2[0];

    // ================= phase 1: fc1+gelu+fc2 over 3328 rows =================
    #pragma unroll 1
    for (int k = 0; k < Cn; ++k) {
        const long g = b0 * Cn + (long)k * 256 + tid;     // row = (b,c) pair
        const float4* xp = reinterpret_cast<const float4*>(ctx + g * Tn);
        float x[Tn];
        #pragma unroll
        for (int i = 0; i < Tn / 4; ++i) {
            float4 v = xp[i];
            x[4 * i + 0] = v.x; x[4 * i + 1] = v.y;
            x[4 * i + 2] = v.z; x[4 * i + 3] = v.w;
        }

        float tacc = 0.0f;
        #pragma unroll 1
        for (int hb = 0; hb < Hn; hb += 16) {
            v2f a2[8];
            const v2f* tb1v = reinterpret_cast<const v2f*>(tb1 + hb);
            #pragma unroll
            for (int j = 0; j < 8; ++j) a2[j] = tb1v[j];
            #pragma unroll
            for (int t = 0; t < Tn; ++t) {
                const float xv = x[t];
                v2f xs = { xv, xv };
                const v2f* wv = reinterpret_cast<const v2f*>(tw1 + t * Hn + hb);
                #pragma unroll
                for (int j = 0; j < 8; ++j)
                    a2[j] = __builtin_elementwise_fma(xs, wv[j], a2[j]);
            }
            #pragma unroll
            for (int j = 0; j < 8; ++j) {
                tacc = fmaf(fast_gelu(a2[j].x), tw2[hb + 2 * j + 0], tacc);
                tacc = fmaf(fast_gelu(a2[j].y), tw2[hb + 2 * j + 1], tacc);
            }
        }
        tv[k * 256 + tid] = tacc + tb2v;
    }

    __syncthreads();

    // ================= phase 2: per-b c_mlp + gumbel + softmax + topk =======
    const long b = b0 + tid;

    float t13[Cn];
    #pragma unroll
    for (int c = 0; c < Cn; ++c) t13[c] = tv[tid * Cn + c];

    float logits[En];
    #pragma unroll
    for (int e = 0; e < En; ++e) logits[e] = cb2[e];

    #pragma unroll 1
    for (int h = 0; h < Hn; ++h) {
        float a = cb1[h];
        #pragma unroll
        for (int c = 0; c < Cn; ++c)
            a = fmaf(t13[c], cw1[c * Hn + h], a);
        float gg = fast_gelu(a);
        #pragma unroll
        for (int e = 0; e < En; ++e)
            logits[e] = fmaf(gg, cw2[h * En + e], logits[e]);
    }

    // gumbel (custom fp64 logs), y = logits + g
    const float4* up = reinterpret_cast<const float4*>(u + b * En);
    float4 u0 = up[0], u1 = up[1];
    float uv[En] = { u0.x, u0.y, u0.z, u0.w, u1.x, u1.y, u1.z, u1.w };

    double y[En];
    #pragma unroll
    for (int e = 0; e < En; ++e) {
        double w = -fast_log((double)uv[e]);
        y[e] = (double)logits[e] - fast_log(w + 1e-10);   // tau = 1
    }

    // softmax in fp32 (probs compared at bf16 tolerance)
    double m = y[0];
    #pragma unroll
    for (int e = 1; e < En; ++e) m = fmax(m, y[e]);
    float p[En], s = 0.0f;
    #pragma unroll
    for (int e = 0; e < En; ++e) {
        p[e] = EXP2F((float)(y[e] - m) * 1.4426950408889634f);
        s += p[e];
    }
    float inv = RCPF(s);

    // top-3 on y (fp64 ordering == probs ordering), bitmask
    unsigned sel = 0u;
    #pragma unroll
    for (int k = 0; k < Kn; ++k) {
        int best = 0;
        double bv = -1.0e300;
        #pragma unroll
        for (int e = 0; e < En; ++e) {
            bool ok = (((sel >> e) & 1u) == 0u) && (y[e] > bv);
            bv = ok ? y[e] : bv;
            best = ok ? e : best;
        }
        sel |= (1u << best);
    }

    // stores
    float4* om = reinterpret_cast<float4*>(out + b * En);
    om[0] = make_float4((sel >> 0) & 1u, (sel >> 1) & 1u,
                        (sel >> 2) & 1u, (sel >> 3) & 1u);
    om[1] = make_float4((sel >> 4) & 1u, (sel >> 5) & 1u,
                        (sel >> 6) & 1u, (sel >> 7) & 1u);
    float4* op = reinterpret_cast<float4*>(out + (long)Bn * En + b * En);
    op[0] = make_float4(p[0] * inv, p[1] * inv, p[2] * inv, p[3] * inv);
    op[1] = make_float4(p[4] * inv, p[5] * inv, p[6] * inv, p[7] * inv);
}

extern "C" void kernel_launch(void* const* d_in, const int* in_sizes, int n_in,
                              void* d_out, int out_size, void* d_ws, size_t ws_size,
                              hipStream_t stream) {
    const float* ctx = (const float*)d_in[0];
    const float* u   = (const float*)d_in[1];
    const float* tw1 = (const float*)d_in[2];
    const float* tb1 = (const float*)d_in[3];
    const float* tw2 = (const float*)d_in[4];
    const float* tb2 = (const float*)d_in[5];
    const float* cw1 = (const float*)d_in[6];
    const float* cb1 = (const float*)d_in[7];
    const float* cw2 = (const float*)d_in[8];
    const float* cb2 = (const float*)d_in[9];
    float* out = (float*)d_out;

    dim3 grid(Bn / 256), block(256);
    router_kernel<<<grid, block, 0, stream>>>(ctx, u, tw1, tb1, tw2, tb2,
                                              cw1, cb1, cw2, cb2, out);
}